// Round 1
// baseline (6666.337 us; speedup 1.0000x reference)
//
#include <hip/hip_runtime.h>

// BotRGCN 4-layer forward, fp32 baseline.
//
// Pipeline:
//  1. count edges per (dst, rel)  -> inv_cnt  (once; layer-invariant)
//  2. encode: xcat[:,0:32]=lrelu(des@W_des+b), [:,32:64]=tweet, [:,64:96]=np, [:,96:128]=cp
//  3. x = lrelu(xcat @ W_in + b_in)
//  4. 4x RGCN layer:
//       agg[n,r,:] = sum_{edges (src->n, type r)} x[src] * inv_cnt[n,r]   (atomic scatter)
//       x' = agg.reshape(N,640) @ rel_w.reshape(640,128) + x @ root_w + rgcn_b
//  5. y = lrelu(x @ W_o1 + b_o1);  out = y @ W_o2 + b_o2

#define N_NODES 50000
#define N_EDGES 800000
#define R_REL   5
#define D_DIM   128

__device__ __forceinline__ float lrelu(float v) { return v > 0.f ? v : 0.01f * v; }

// ---------------- edge counting ----------------
__global__ __launch_bounds__(256) void count_kernel(const int* __restrict__ ei,
                                                    const int* __restrict__ et,
                                                    int* __restrict__ cnt) {
    int e = blockIdx.x * 256 + threadIdx.x;
    if (e >= N_EDGES) return;
    int dst = ei[N_EDGES + e];
    int ty  = et[e];
    atomicAdd(&cnt[dst * R_REL + ty], 1);
}

__global__ __launch_bounds__(256) void inv_kernel(const int* __restrict__ cnt,
                                                  float* __restrict__ inv) {
    int i = blockIdx.x * 256 + threadIdx.x;
    if (i >= N_NODES * R_REL) return;
    int c = cnt[i];
    inv[i] = 1.0f / (float)(c > 1 ? c : 1);
}

// ---------------- small feature encoders (K=6, K=11) ----------------
__global__ __launch_bounds__(256) void encode_small(const float* __restrict__ num_prop,
                                                    const float* __restrict__ cat_prop,
                                                    const float* __restrict__ W_np,
                                                    const float* __restrict__ b_np,
                                                    const float* __restrict__ W_cp,
                                                    const float* __restrict__ b_cp,
                                                    float* __restrict__ x) {
    int t = blockIdx.x * 256 + threadIdx.x;
    int node = t >> 6;
    int jj = t & 63;
    if (node >= N_NODES) return;
    if (jj < 32) {
        float acc = b_np[jj];
        const float* row = num_prop + (size_t)node * 6;
#pragma unroll
        for (int k = 0; k < 6; k++) acc = fmaf(row[k], W_np[k * 32 + jj], acc);
        x[(size_t)node * 128 + 64 + jj] = lrelu(acc);
    } else {
        int j = jj - 32;
        float acc = b_cp[j];
        const float* row = cat_prop + (size_t)node * 11;
#pragma unroll
        for (int k = 0; k < 11; k++) acc = fmaf(row[k], W_cp[k * 32 + j], acc);
        x[(size_t)node * 128 + 96 + j] = lrelu(acc);
    }
}

// ---------------- K=768 -> 32 encoder GEMM (des / tweet) ----------------
// C[m, colofs + j] = lrelu(A[m,:] @ W[:,j] + b[j]),  C has row stride 128.
__global__ __launch_bounds__(256) void gemm_k768_n32(const float* __restrict__ A,
                                                     const float* __restrict__ W,
                                                     const float* __restrict__ bias,
                                                     float* __restrict__ C,
                                                     int M, int colofs) {
    __shared__ float As[128][36];
    __shared__ float Ws[32][33];
    const int t = threadIdx.x;
    const int tj = t & 31, tm = t >> 5;       // tm in 0..7
    const int m0 = blockIdx.x * 128;
    float acc[16];
#pragma unroll
    for (int i = 0; i < 16; i++) acc[i] = 0.f;

    for (int kc = 0; kc < 768; kc += 32) {
#pragma unroll
        for (int i = 0; i < 4; i++) {
            int f4 = t + i * 256;
            int row = f4 >> 3, c4 = f4 & 7;
            int gr = m0 + row; if (gr >= M) gr = M - 1;
            *(float4*)&As[row][c4 * 4] =
                *(const float4*)(A + (size_t)gr * 768 + kc + c4 * 4);
        }
#pragma unroll
        for (int i = 0; i < 4; i++) {
            int idx = t + i * 256;
            int kr = idx >> 5, cc = idx & 31;
            Ws[kr][cc] = W[(size_t)(kc + kr) * 32 + cc];
        }
        __syncthreads();
#pragma unroll
        for (int k = 0; k < 32; k++) {
            float w = Ws[k][tj];
#pragma unroll
            for (int mm = 0; mm < 16; mm++)
                acc[mm] = fmaf(As[tm * 16 + mm][k], w, acc[mm]);
        }
        __syncthreads();
    }
    float b = bias[tj];
#pragma unroll
    for (int mm = 0; mm < 16; mm++) {
        int m = m0 + tm * 16 + mm;
        if (m < M) C[(size_t)m * 128 + colofs + tj] = lrelu(acc[mm] + b);
    }
}

// ---------------- generic N=128-output GEMM ----------------
// C[M,128] = act( A1[M,K1] @ W1[K1,128] (+ A2[M,128] @ W2[128,128]) + b )
template <bool ACT, bool DUAL>
__global__ __launch_bounds__(256) void gemm_n128(const float* __restrict__ A1,
                                                 const float* __restrict__ W1, int K1,
                                                 const float* __restrict__ A2,
                                                 const float* __restrict__ W2,
                                                 const float* __restrict__ bias,
                                                 float* __restrict__ C, int M) {
    __shared__ float As[64][36];
    __shared__ float Ws[32][128];
    const int t = threadIdx.x;
    const int tj = t & 31, tm = t >> 5;       // tm in 0..7
    const int m0 = blockIdx.x * 64;
    float acc[8][4];
#pragma unroll
    for (int i = 0; i < 8; i++)
#pragma unroll
        for (int j = 0; j < 4; j++) acc[i][j] = 0.f;

    const int nphase = DUAL ? 2 : 1;
    for (int phase = 0; phase < nphase; ++phase) {
        const float* A = phase ? A2 : A1;
        const float* W = phase ? W2 : W1;
        const int K = phase ? 128 : K1;
        for (int kc = 0; kc < K; kc += 32) {
#pragma unroll
            for (int i = 0; i < 2; i++) {
                int f4 = t + i * 256;
                int row = f4 >> 3, c4 = f4 & 7;
                int gr = m0 + row; if (gr >= M) gr = M - 1;
                *(float4*)&As[row][c4 * 4] =
                    *(const float4*)(A + (size_t)gr * K + kc + c4 * 4);
            }
#pragma unroll
            for (int i = 0; i < 4; i++) {
                int f4 = t + i * 256;
                int kr = f4 >> 5, c4 = f4 & 31;
                *(float4*)&Ws[kr][c4 * 4] =
                    *(const float4*)(W + (size_t)(kc + kr) * 128 + c4 * 4);
            }
            __syncthreads();
#pragma unroll
            for (int k = 0; k < 32; k++) {
                float4 w = *(const float4*)&Ws[k][tj * 4];
#pragma unroll
                for (int mm = 0; mm < 8; mm++) {
                    float a = As[tm * 8 + mm][k];
                    acc[mm][0] = fmaf(a, w.x, acc[mm][0]);
                    acc[mm][1] = fmaf(a, w.y, acc[mm][1]);
                    acc[mm][2] = fmaf(a, w.z, acc[mm][2]);
                    acc[mm][3] = fmaf(a, w.w, acc[mm][3]);
                }
            }
            __syncthreads();
        }
    }
    float4 b = *(const float4*)(bias + tj * 4);
#pragma unroll
    for (int mm = 0; mm < 8; mm++) {
        int m = m0 + tm * 8 + mm;
        if (m < M) {
            float4 c;
            c.x = acc[mm][0] + b.x;
            c.y = acc[mm][1] + b.y;
            c.z = acc[mm][2] + b.z;
            c.w = acc[mm][3] + b.w;
            if (ACT) { c.x = lrelu(c.x); c.y = lrelu(c.y); c.z = lrelu(c.z); c.w = lrelu(c.w); }
            *(float4*)(C + (size_t)m * 128 + tj * 4) = c;
        }
    }
}

// ---------------- edge scatter: agg[dst,ty,:] += x[src,:] * inv_cnt ----------------
__global__ __launch_bounds__(256) void scatter_kernel(const float* __restrict__ x,
                                                      const int* __restrict__ ei,
                                                      const int* __restrict__ et,
                                                      const float* __restrict__ inv_cnt,
                                                      float* __restrict__ agg) {
    int t = blockIdx.x * 256 + threadIdx.x;
    int e = t >> 5;            // 32 threads per edge
    if (e >= N_EDGES) return;
    int lane = t & 31;
    int src = ei[e];
    int dst = ei[N_EDGES + e];
    int ty  = et[e];
    int seg = dst * R_REL + ty;
    float s = inv_cnt[seg];
    float4 v = ((const float4*)(x + (size_t)src * 128))[lane];
    float* base = agg + (size_t)seg * 128 + lane * 4;
    atomicAdd(base + 0, v.x * s);
    atomicAdd(base + 1, v.y * s);
    atomicAdd(base + 2, v.z * s);
    atomicAdd(base + 3, v.w * s);
}

// ---------------- final projection 128 -> 2 ----------------
__global__ __launch_bounds__(256) void out_proj(const float* __restrict__ X,
                                                const float* __restrict__ W,
                                                const float* __restrict__ b,
                                                float* __restrict__ out, int M) {
    int n = blockIdx.x * 256 + threadIdx.x;
    if (n >= M) return;
    float a0 = b[0], a1 = b[1];
    const float4* xr = (const float4*)(X + (size_t)n * 128);
#pragma unroll
    for (int k4 = 0; k4 < 32; k4++) {
        float4 v = xr[k4];
        a0 = fmaf(v.x, W[(k4 * 4 + 0) * 2 + 0], a0);
        a1 = fmaf(v.x, W[(k4 * 4 + 0) * 2 + 1], a1);
        a0 = fmaf(v.y, W[(k4 * 4 + 1) * 2 + 0], a0);
        a1 = fmaf(v.y, W[(k4 * 4 + 1) * 2 + 1], a1);
        a0 = fmaf(v.z, W[(k4 * 4 + 2) * 2 + 0], a0);
        a1 = fmaf(v.z, W[(k4 * 4 + 2) * 2 + 1], a1);
        a0 = fmaf(v.w, W[(k4 * 4 + 3) * 2 + 0], a0);
        a1 = fmaf(v.w, W[(k4 * 4 + 3) * 2 + 1], a1);
    }
    out[(size_t)n * 2 + 0] = a0;
    out[(size_t)n * 2 + 1] = a1;
}

extern "C" void kernel_launch(void* const* d_in, const int* in_sizes, int n_in,
                              void* d_out, int out_size, void* d_ws, size_t ws_size,
                              hipStream_t stream) {
    const float* des      = (const float*)d_in[0];
    const float* tweet    = (const float*)d_in[1];
    const float* num_prop = (const float*)d_in[2];
    const float* cat_prop = (const float*)d_in[3];
    const int*   edge_index = (const int*)d_in[4];
    const int*   edge_type  = (const int*)d_in[5];
    const float* W_des = (const float*)d_in[6];  const float* b_des = (const float*)d_in[7];
    const float* W_tw  = (const float*)d_in[8];  const float* b_tw  = (const float*)d_in[9];
    const float* W_np  = (const float*)d_in[10]; const float* b_np  = (const float*)d_in[11];
    const float* W_cp  = (const float*)d_in[12]; const float* b_cp  = (const float*)d_in[13];
    const float* W_in  = (const float*)d_in[14]; const float* b_in  = (const float*)d_in[15];
    const float* rel_w = (const float*)d_in[16]; const float* root_w = (const float*)d_in[17];
    const float* rgcn_b = (const float*)d_in[18];
    const float* W_o1  = (const float*)d_in[19]; const float* b_o1  = (const float*)d_in[20];
    const float* W_o2  = (const float*)d_in[21]; const float* b_o2  = (const float*)d_in[22];
    float* out = (float*)d_out;

    // workspace layout
    float* agg = (float*)d_ws;                                      // N*R*128 f32 = 128 MB
    float* xA  = agg + (size_t)N_NODES * R_REL * 128;               // N*128
    float* xB  = xA + (size_t)N_NODES * 128;                        // N*128
    float* inv_cnt = xB + (size_t)N_NODES * 128;                    // N*R
    int*   cnt = (int*)(inv_cnt + (size_t)N_NODES * R_REL);         // N*R

    // 1. edge counts (layer-invariant)
    hipMemsetAsync(cnt, 0, (size_t)N_NODES * R_REL * sizeof(int), stream);
    count_kernel<<<(N_EDGES + 255) / 256, 256, 0, stream>>>(edge_index, edge_type, cnt);
    inv_kernel<<<(N_NODES * R_REL + 255) / 256, 256, 0, stream>>>(cnt, inv_cnt);

    // 2. encode
    encode_small<<<(N_NODES * 64 + 255) / 256, 256, 0, stream>>>(
        num_prop, cat_prop, W_np, b_np, W_cp, b_cp, xA);
    gemm_k768_n32<<<(N_NODES + 127) / 128, 256, 0, stream>>>(des, W_des, b_des, xA, N_NODES, 0);
    gemm_k768_n32<<<(N_NODES + 127) / 128, 256, 0, stream>>>(tweet, W_tw, b_tw, xA, N_NODES, 32);

    // 3. input linear
    gemm_n128<true, false><<<(N_NODES + 63) / 64, 256, 0, stream>>>(
        xA, W_in, 128, nullptr, nullptr, b_in, xB, N_NODES);

    // 4. RGCN x4
    float* cur = xB; float* nxt = xA;
    for (int l = 0; l < 4; l++) {
        hipMemsetAsync(agg, 0, (size_t)N_NODES * R_REL * 128 * sizeof(float), stream);
        scatter_kernel<<<(N_EDGES * 32) / 256, 256, 0, stream>>>(
            cur, edge_index, edge_type, inv_cnt, agg);
        gemm_n128<false, true><<<(N_NODES + 63) / 64, 256, 0, stream>>>(
            agg, rel_w, R_REL * 128, cur, root_w, rgcn_b, nxt, N_NODES);
        float* tmp = cur; cur = nxt; nxt = tmp;
    }

    // 5. output head
    gemm_n128<true, false><<<(N_NODES + 63) / 64, 256, 0, stream>>>(
        cur, W_o1, 128, nullptr, nullptr, b_o1, nxt, N_NODES);
    out_proj<<<(N_NODES + 255) / 256, 256, 0, stream>>>(nxt, W_o2, b_o2, out, N_NODES);
}

// Round 2
// 1699.050 us; speedup vs baseline: 3.9236x; 3.9236x over previous
//
#include <hip/hip_runtime.h>

// BotRGCN 4-layer forward, fp32.
//
// Round 2: replace atomic scatter (1.35 ms/layer, 1.6 GB HBM writes from
// atomic L2 thrash) with CSR-sorted gather-reduce (no atomics, agg written
// exactly once). CSR built in-graph each launch (layer-invariant).
//
// Pipeline:
//  1. count edges per seg=(dst*R+rel); exclusive-scan -> rowptr; bucket-fill srcSorted
//  2. encode: x[:,0:32]=lrelu(des@W_des+b), [:,32:64]=tweet, [:,64:96]=np, [:,96:128]=cp
//  3. x = lrelu(x @ W_in + b_in)
//  4. 4x RGCN: agg[seg,:] = mean_{e in seg} x[src_e]  (gather), then
//     x' = agg.reshape(N,640) @ rel_w.reshape(640,128) + x @ root_w + rgcn_b
//  5. y = lrelu(x @ W_o1 + b_o1); out = y @ W_o2 + b_o2

#define N_NODES 50000
#define N_EDGES 800000
#define R_REL   5
#define NSEG    (N_NODES * R_REL)   // 250000
#define SCAN_BS 1024
#define SCAN_NB ((NSEG + SCAN_BS - 1) / SCAN_BS)   // 245

__device__ __forceinline__ float lrelu(float v) { return v > 0.f ? v : 0.01f * v; }

// ---------------- CSR build ----------------
__global__ __launch_bounds__(256) void count_kernel(const int* __restrict__ ei,
                                                    const int* __restrict__ et,
                                                    int* __restrict__ cnt) {
    int e = blockIdx.x * 256 + threadIdx.x;
    if (e >= N_EDGES) return;
    int dst = ei[N_EDGES + e];
    int ty  = et[e];
    atomicAdd(&cnt[dst * R_REL + ty], 1);
}

// block-level exclusive scan (Hillis-Steele in LDS), emits per-block sums
__global__ __launch_bounds__(SCAN_BS) void scan1(const int* __restrict__ cnt,
                                                 int* __restrict__ rowptr,
                                                 int* __restrict__ blockSums) {
    __shared__ int s[SCAN_BS];
    int t = threadIdx.x;
    int i = blockIdx.x * SCAN_BS + t;
    int v = (i < NSEG) ? cnt[i] : 0;
    s[t] = v;
    __syncthreads();
#pragma unroll
    for (int off = 1; off < SCAN_BS; off <<= 1) {
        int add = (t >= off) ? s[t - off] : 0;
        __syncthreads();
        s[t] += add;
        __syncthreads();
    }
    if (i < NSEG) rowptr[i] = s[t] - v;   // exclusive within block
    if (t == SCAN_BS - 1) blockSums[blockIdx.x] = s[t];
}

// exclusive scan of the (<=256) block sums, single block
__global__ __launch_bounds__(256) void scan2(int* __restrict__ blockSums) {
    __shared__ int s[256];
    int t = threadIdx.x;
    int v = (t < SCAN_NB) ? blockSums[t] : 0;
    s[t] = v;
    __syncthreads();
#pragma unroll
    for (int off = 1; off < 256; off <<= 1) {
        int add = (t >= off) ? s[t - off] : 0;
        __syncthreads();
        s[t] += add;
        __syncthreads();
    }
    if (t < SCAN_NB) blockSums[t] = s[t] - v;  // exclusive
}

__global__ __launch_bounds__(SCAN_BS) void scan3(int* __restrict__ rowptr,
                                                 const int* __restrict__ blockSums) {
    int i = blockIdx.x * SCAN_BS + threadIdx.x;
    if (i == 0) rowptr[NSEG] = N_EDGES;
    if (i < NSEG) rowptr[i] += blockSums[blockIdx.x];
}

__global__ __launch_bounds__(256) void fill_kernel(const int* __restrict__ ei,
                                                   const int* __restrict__ et,
                                                   const int* __restrict__ rowptr,
                                                   int* __restrict__ cursor,
                                                   int* __restrict__ srcSorted) {
    int e = blockIdx.x * 256 + threadIdx.x;
    if (e >= N_EDGES) return;
    int src = ei[e];
    int dst = ei[N_EDGES + e];
    int ty  = et[e];
    int seg = dst * R_REL + ty;
    int pos = atomicAdd(&cursor[seg], 1);
    srcSorted[rowptr[seg] + pos] = src;
}

// ---------------- gather-reduce aggregation ----------------
// one 64-lane wave per segment; lane covers 2 of 128 columns
__global__ __launch_bounds__(256) void agg_kernel(const float* __restrict__ x,
                                                  const int* __restrict__ srcSorted,
                                                  const int* __restrict__ rowptr,
                                                  float* __restrict__ agg) {
    int t = blockIdx.x * 256 + threadIdx.x;
    int seg = t >> 6;
    if (seg >= NSEG) return;
    int lane = t & 63;
    int beg = rowptr[seg], end = rowptr[seg + 1];
    float ax = 0.f, ay = 0.f;
    for (int i = beg; i < end; i++) {
        int src = srcSorted[i];
        float2 v = *(const float2*)(x + (size_t)src * 128 + lane * 2);
        ax += v.x; ay += v.y;
    }
    int c = end - beg;
    float s = 1.0f / (float)(c > 1 ? c : 1);
    *(float2*)(agg + (size_t)seg * 128 + lane * 2) = make_float2(ax * s, ay * s);
}

// ---------------- small feature encoders (K=6, K=11) ----------------
__global__ __launch_bounds__(256) void encode_small(const float* __restrict__ num_prop,
                                                    const float* __restrict__ cat_prop,
                                                    const float* __restrict__ W_np,
                                                    const float* __restrict__ b_np,
                                                    const float* __restrict__ W_cp,
                                                    const float* __restrict__ b_cp,
                                                    float* __restrict__ x) {
    int t = blockIdx.x * 256 + threadIdx.x;
    int node = t >> 6;
    int jj = t & 63;
    if (node >= N_NODES) return;
    if (jj < 32) {
        float acc = b_np[jj];
        const float* row = num_prop + (size_t)node * 6;
#pragma unroll
        for (int k = 0; k < 6; k++) acc = fmaf(row[k], W_np[k * 32 + jj], acc);
        x[(size_t)node * 128 + 64 + jj] = lrelu(acc);
    } else {
        int j = jj - 32;
        float acc = b_cp[j];
        const float* row = cat_prop + (size_t)node * 11;
#pragma unroll
        for (int k = 0; k < 11; k++) acc = fmaf(row[k], W_cp[k * 32 + j], acc);
        x[(size_t)node * 128 + 96 + j] = lrelu(acc);
    }
}

// ---------------- K=768 -> 32 encoder GEMM (des / tweet) ----------------
__global__ __launch_bounds__(256) void gemm_k768_n32(const float* __restrict__ A,
                                                     const float* __restrict__ W,
                                                     const float* __restrict__ bias,
                                                     float* __restrict__ C,
                                                     int M, int colofs) {
    __shared__ float As[128][36];
    __shared__ float Ws[32][33];
    const int t = threadIdx.x;
    const int tj = t & 31, tm = t >> 5;
    const int m0 = blockIdx.x * 128;
    float acc[16];
#pragma unroll
    for (int i = 0; i < 16; i++) acc[i] = 0.f;

    for (int kc = 0; kc < 768; kc += 32) {
#pragma unroll
        for (int i = 0; i < 4; i++) {
            int f4 = t + i * 256;
            int row = f4 >> 3, c4 = f4 & 7;
            int gr = m0 + row; if (gr >= M) gr = M - 1;
            *(float4*)&As[row][c4 * 4] =
                *(const float4*)(A + (size_t)gr * 768 + kc + c4 * 4);
        }
#pragma unroll
        for (int i = 0; i < 4; i++) {
            int idx = t + i * 256;
            int kr = idx >> 5, cc = idx & 31;
            Ws[kr][cc] = W[(size_t)(kc + kr) * 32 + cc];
        }
        __syncthreads();
#pragma unroll
        for (int k = 0; k < 32; k++) {
            float w = Ws[k][tj];
#pragma unroll
            for (int mm = 0; mm < 16; mm++)
                acc[mm] = fmaf(As[tm * 16 + mm][k], w, acc[mm]);
        }
        __syncthreads();
    }
    float b = bias[tj];
#pragma unroll
    for (int mm = 0; mm < 16; mm++) {
        int m = m0 + tm * 16 + mm;
        if (m < M) C[(size_t)m * 128 + colofs + tj] = lrelu(acc[mm] + b);
    }
}

// ---------------- generic N=128-output GEMM ----------------
template <bool ACT, bool DUAL>
__global__ __launch_bounds__(256) void gemm_n128(const float* __restrict__ A1,
                                                 const float* __restrict__ W1, int K1,
                                                 const float* __restrict__ A2,
                                                 const float* __restrict__ W2,
                                                 const float* __restrict__ bias,
                                                 float* __restrict__ C, int M) {
    __shared__ float As[64][36];
    __shared__ float Ws[32][128];
    const int t = threadIdx.x;
    const int tj = t & 31, tm = t >> 5;
    const int m0 = blockIdx.x * 64;
    float acc[8][4];
#pragma unroll
    for (int i = 0; i < 8; i++)
#pragma unroll
        for (int j = 0; j < 4; j++) acc[i][j] = 0.f;

    const int nphase = DUAL ? 2 : 1;
    for (int phase = 0; phase < nphase; ++phase) {
        const float* A = phase ? A2 : A1;
        const float* W = phase ? W2 : W1;
        const int K = phase ? 128 : K1;
        for (int kc = 0; kc < K; kc += 32) {
#pragma unroll
            for (int i = 0; i < 2; i++) {
                int f4 = t + i * 256;
                int row = f4 >> 3, c4 = f4 & 7;
                int gr = m0 + row; if (gr >= M) gr = M - 1;
                *(float4*)&As[row][c4 * 4] =
                    *(const float4*)(A + (size_t)gr * K + kc + c4 * 4);
            }
#pragma unroll
            for (int i = 0; i < 4; i++) {
                int f4 = t + i * 256;
                int kr = f4 >> 5, c4 = f4 & 31;
                *(float4*)&Ws[kr][c4 * 4] =
                    *(const float4*)(W + (size_t)(kc + kr) * 128 + c4 * 4);
            }
            __syncthreads();
#pragma unroll
            for (int k = 0; k < 32; k++) {
                float4 w = *(const float4*)&Ws[k][tj * 4];
#pragma unroll
                for (int mm = 0; mm < 8; mm++) {
                    float a = As[tm * 8 + mm][k];
                    acc[mm][0] = fmaf(a, w.x, acc[mm][0]);
                    acc[mm][1] = fmaf(a, w.y, acc[mm][1]);
                    acc[mm][2] = fmaf(a, w.z, acc[mm][2]);
                    acc[mm][3] = fmaf(a, w.w, acc[mm][3]);
                }
            }
            __syncthreads();
        }
    }
    float4 b = *(const float4*)(bias + tj * 4);
#pragma unroll
    for (int mm = 0; mm < 8; mm++) {
        int m = m0 + tm * 8 + mm;
        if (m < M) {
            float4 c;
            c.x = acc[mm][0] + b.x;
            c.y = acc[mm][1] + b.y;
            c.z = acc[mm][2] + b.z;
            c.w = acc[mm][3] + b.w;
            if (ACT) { c.x = lrelu(c.x); c.y = lrelu(c.y); c.z = lrelu(c.z); c.w = lrelu(c.w); }
            *(float4*)(C + (size_t)m * 128 + tj * 4) = c;
        }
    }
}

// ---------------- final projection 128 -> 2 ----------------
__global__ __launch_bounds__(256) void out_proj(const float* __restrict__ X,
                                                const float* __restrict__ W,
                                                const float* __restrict__ b,
                                                float* __restrict__ out, int M) {
    int n = blockIdx.x * 256 + threadIdx.x;
    if (n >= M) return;
    float a0 = b[0], a1 = b[1];
    const float4* xr = (const float4*)(X + (size_t)n * 128);
#pragma unroll
    for (int k4 = 0; k4 < 32; k4++) {
        float4 v = xr[k4];
        a0 = fmaf(v.x, W[(k4 * 4 + 0) * 2 + 0], a0);
        a1 = fmaf(v.x, W[(k4 * 4 + 0) * 2 + 1], a1);
        a0 = fmaf(v.y, W[(k4 * 4 + 1) * 2 + 0], a0);
        a1 = fmaf(v.y, W[(k4 * 4 + 1) * 2 + 1], a1);
        a0 = fmaf(v.z, W[(k4 * 4 + 2) * 2 + 0], a0);
        a1 = fmaf(v.z, W[(k4 * 4 + 2) * 2 + 1], a1);
        a0 = fmaf(v.w, W[(k4 * 4 + 3) * 2 + 0], a0);
        a1 = fmaf(v.w, W[(k4 * 4 + 3) * 2 + 1], a1);
    }
    out[(size_t)n * 2 + 0] = a0;
    out[(size_t)n * 2 + 1] = a1;
}

extern "C" void kernel_launch(void* const* d_in, const int* in_sizes, int n_in,
                              void* d_out, int out_size, void* d_ws, size_t ws_size,
                              hipStream_t stream) {
    const float* des      = (const float*)d_in[0];
    const float* tweet    = (const float*)d_in[1];
    const float* num_prop = (const float*)d_in[2];
    const float* cat_prop = (const float*)d_in[3];
    const int*   edge_index = (const int*)d_in[4];
    const int*   edge_type  = (const int*)d_in[5];
    const float* W_des = (const float*)d_in[6];  const float* b_des = (const float*)d_in[7];
    const float* W_tw  = (const float*)d_in[8];  const float* b_tw  = (const float*)d_in[9];
    const float* W_np  = (const float*)d_in[10]; const float* b_np  = (const float*)d_in[11];
    const float* W_cp  = (const float*)d_in[12]; const float* b_cp  = (const float*)d_in[13];
    const float* W_in  = (const float*)d_in[14]; const float* b_in  = (const float*)d_in[15];
    const float* rel_w = (const float*)d_in[16]; const float* root_w = (const float*)d_in[17];
    const float* rgcn_b = (const float*)d_in[18];
    const float* W_o1  = (const float*)d_in[19]; const float* b_o1  = (const float*)d_in[20];
    const float* W_o2  = (const float*)d_in[21]; const float* b_o2  = (const float*)d_in[22];
    float* out = (float*)d_out;

    // workspace layout
    float* agg = (float*)d_ws;                                  // NSEG*128 f32 = 128 MB
    float* xA  = agg + (size_t)NSEG * 128;                      // N*128 = 25.6 MB
    float* xB  = xA + (size_t)N_NODES * 128;                    // N*128 = 25.6 MB
    int* cnt       = (int*)(xB + (size_t)N_NODES * 128);        // NSEG
    int* rowptr    = cnt + NSEG;                                // NSEG+1
    int* cursor    = rowptr + NSEG + 1;                         // NSEG
    int* srcSorted = cursor + NSEG;                             // E
    int* blockSums = srcSorted + N_EDGES;                       // SCAN_NB (<=256)

    // 1. CSR build (layer-invariant)
    hipMemsetAsync(cnt, 0, (size_t)NSEG * sizeof(int), stream);
    hipMemsetAsync(cursor, 0, (size_t)NSEG * sizeof(int), stream);
    count_kernel<<<(N_EDGES + 255) / 256, 256, 0, stream>>>(edge_index, edge_type, cnt);
    scan1<<<SCAN_NB, SCAN_BS, 0, stream>>>(cnt, rowptr, blockSums);
    scan2<<<1, 256, 0, stream>>>(blockSums);
    scan3<<<SCAN_NB, SCAN_BS, 0, stream>>>(rowptr, blockSums);
    fill_kernel<<<(N_EDGES + 255) / 256, 256, 0, stream>>>(
        edge_index, edge_type, rowptr, cursor, srcSorted);

    // 2. encode
    encode_small<<<(N_NODES * 64 + 255) / 256, 256, 0, stream>>>(
        num_prop, cat_prop, W_np, b_np, W_cp, b_cp, xA);
    gemm_k768_n32<<<(N_NODES + 127) / 128, 256, 0, stream>>>(des, W_des, b_des, xA, N_NODES, 0);
    gemm_k768_n32<<<(N_NODES + 127) / 128, 256, 0, stream>>>(tweet, W_tw, b_tw, xA, N_NODES, 32);

    // 3. input linear
    gemm_n128<true, false><<<(N_NODES + 63) / 64, 256, 0, stream>>>(
        xA, W_in, 128, nullptr, nullptr, b_in, xB, N_NODES);

    // 4. RGCN x4 (gather aggregation, no atomics, no memset)
    float* cur = xB; float* nxt = xA;
    for (int l = 0; l < 4; l++) {
        agg_kernel<<<(NSEG * 64 + 255) / 256, 256, 0, stream>>>(cur, srcSorted, rowptr, agg);
        gemm_n128<false, true><<<(N_NODES + 63) / 64, 256, 0, stream>>>(
            agg, rel_w, R_REL * 128, cur, root_w, rgcn_b, nxt, N_NODES);
        float* tmp = cur; cur = nxt; nxt = tmp;
    }

    // 5. output head
    gemm_n128<true, false><<<(N_NODES + 63) / 64, 256, 0, stream>>>(
        cur, W_o1, 128, nullptr, nullptr, b_o1, nxt, N_NODES);
    out_proj<<<(N_NODES + 255) / 256, 256, 0, stream>>>(nxt, W_o2, b_o2, out, N_NODES);
}

// Round 3
// 1415.893 us; speedup vs baseline: 4.7082x; 1.2000x over previous
//
#include <hip/hip_runtime.h>

// BotRGCN 4-layer forward.
// Round 3: all N=128-output GEMMs -> MFMA bf16x3 split (fp32-class accuracy).
// Weights pre-split+transposed once per launch; A split on the fly in staging.

#define N_NODES 50000
#define N_EDGES 800000
#define R_REL   5
#define NSEG    (N_NODES * R_REL)   // 250000
#define SCAN_BS 1024
#define SCAN_NB ((NSEG + SCAN_BS - 1) / SCAN_BS)   // 245

typedef __attribute__((ext_vector_type(8))) short bf16x8;
typedef __attribute__((ext_vector_type(4))) float f32x4;

__device__ __forceinline__ float lrelu(float v) { return v > 0.f ? v : 0.01f * v; }

__device__ __forceinline__ unsigned short f2bf_rne(float f) {
    unsigned u = __float_as_uint(f);
    return (unsigned short)((u + 0x7fff + ((u >> 16) & 1)) >> 16);
}

// split 8 consecutive floats into bf16 hi (truncation) + lo (RNE of residual)
__device__ __forceinline__ void split8(const float* f, bf16x8& hi, bf16x8& lo) {
#pragma unroll
    for (int i = 0; i < 8; i++) {
        unsigned u = __float_as_uint(f[i]);
        unsigned short h = (unsigned short)(u >> 16);
        float hf = __uint_as_float((unsigned)h << 16);
        float l = f[i] - hf;
        hi[i] = (short)h;
        lo[i] = (short)f2bf_rne(l);
    }
}

// ---------------- CSR build ----------------
__global__ __launch_bounds__(256) void count_kernel(const int* __restrict__ ei,
                                                    const int* __restrict__ et,
                                                    int* __restrict__ cnt) {
    int e = blockIdx.x * 256 + threadIdx.x;
    if (e >= N_EDGES) return;
    atomicAdd(&cnt[ei[N_EDGES + e] * R_REL + et[e]], 1);
}

__global__ __launch_bounds__(SCAN_BS) void scan1(const int* __restrict__ cnt,
                                                 int* __restrict__ rowptr,
                                                 int* __restrict__ blockSums) {
    __shared__ int s[SCAN_BS];
    int t = threadIdx.x;
    int i = blockIdx.x * SCAN_BS + t;
    int v = (i < NSEG) ? cnt[i] : 0;
    s[t] = v;
    __syncthreads();
#pragma unroll
    for (int off = 1; off < SCAN_BS; off <<= 1) {
        int add = (t >= off) ? s[t - off] : 0;
        __syncthreads();
        s[t] += add;
        __syncthreads();
    }
    if (i < NSEG) rowptr[i] = s[t] - v;
    if (t == SCAN_BS - 1) blockSums[blockIdx.x] = s[t];
}

__global__ __launch_bounds__(256) void scan2(int* __restrict__ blockSums) {
    __shared__ int s[256];
    int t = threadIdx.x;
    int v = (t < SCAN_NB) ? blockSums[t] : 0;
    s[t] = v;
    __syncthreads();
#pragma unroll
    for (int off = 1; off < 256; off <<= 1) {
        int add = (t >= off) ? s[t - off] : 0;
        __syncthreads();
        s[t] += add;
        __syncthreads();
    }
    if (t < SCAN_NB) blockSums[t] = s[t] - v;
}

__global__ __launch_bounds__(SCAN_BS) void scan3(int* __restrict__ rowptr,
                                                 const int* __restrict__ blockSums) {
    int i = blockIdx.x * SCAN_BS + threadIdx.x;
    if (i == 0) rowptr[NSEG] = N_EDGES;
    if (i < NSEG) rowptr[i] += blockSums[blockIdx.x];
}

__global__ __launch_bounds__(256) void fill_kernel(const int* __restrict__ ei,
                                                   const int* __restrict__ et,
                                                   const int* __restrict__ rowptr,
                                                   int* __restrict__ cursor,
                                                   int* __restrict__ srcSorted) {
    int e = blockIdx.x * 256 + threadIdx.x;
    if (e >= N_EDGES) return;
    int seg = ei[N_EDGES + e] * R_REL + et[e];
    int pos = atomicAdd(&cursor[seg], 1);
    srcSorted[rowptr[seg] + pos] = ei[e];
}

// ---------------- gather-reduce aggregation ----------------
__global__ __launch_bounds__(256) void agg_kernel(const float* __restrict__ x,
                                                  const int* __restrict__ srcSorted,
                                                  const int* __restrict__ rowptr,
                                                  float* __restrict__ agg) {
    int t = blockIdx.x * 256 + threadIdx.x;
    int seg = t >> 6;
    if (seg >= NSEG) return;
    int lane = t & 63;
    int beg = rowptr[seg], end = rowptr[seg + 1];
    float ax = 0.f, ay = 0.f;
    for (int i = beg; i < end; i++) {
        int src = srcSorted[i];
        float2 v = *(const float2*)(x + (size_t)src * 128 + lane * 2);
        ax += v.x; ay += v.y;
    }
    int c = end - beg;
    float s = 1.0f / (float)(c > 1 ? c : 1);
    *(float2*)(agg + (size_t)seg * 128 + lane * 2) = make_float2(ax * s, ay * s);
}

// ---------------- weight prep: fp32 [K][128] -> bf16 hi/lo transposed [128][K] ----------------
__global__ __launch_bounds__(256) void split_transpose(const float* __restrict__ W,
                                                       short* __restrict__ Whi,
                                                       short* __restrict__ Wlo, int K) {
    int idx = blockIdx.x * 256 + threadIdx.x;
    if (idx >= K * 128) return;
    int k = idx >> 7, n = idx & 127;
    float w = W[idx];
    unsigned u = __float_as_uint(w);
    unsigned short h = (unsigned short)(u >> 16);
    float hf = __uint_as_float((unsigned)h << 16);
    unsigned short l = f2bf_rne(w - hf);
    Whi[(size_t)n * K + k] = (short)h;
    Wlo[(size_t)n * K + k] = (short)l;
}

// ---------------- MFMA bf16x3 GEMM, N=128 outputs ----------------
// C[M,128] = act( A1[M,K1]@W1 (+ A2[M,128]@W2) + bias )
// B planes are n-major bf16: Bhi/Blo[n][k], n<128.
// Block: 128 threads (2 waves), 64 rows. Wave w: rows w*32..w*32+31 (2 m-tiles).
template <bool ACT, bool DUAL>
__global__ __launch_bounds__(128) void mfma_gemm(const float* __restrict__ A1, int K1,
                                                 const short* __restrict__ B1hi,
                                                 const short* __restrict__ B1lo,
                                                 const float* __restrict__ A2,
                                                 const short* __restrict__ B2hi,
                                                 const short* __restrict__ B2lo,
                                                 const float* __restrict__ bias,
                                                 float* __restrict__ C, int M) {
    __shared__ short Ahi[64][40], Alo[64][40];
    __shared__ short Bhi[128][40], Blo[128][40];
    const int t = threadIdx.x;
    const int m0 = blockIdx.x * 64;
    const int w = t >> 6, lane = t & 63;
    const int q = lane >> 4, ln = lane & 15;

    f32x4 acc[2][8];
#pragma unroll
    for (int mt = 0; mt < 2; mt++)
#pragma unroll
        for (int nt = 0; nt < 8; nt++) acc[mt][nt] = (f32x4)0.f;

    const int nchunks1 = K1 / 32;
    const int nchunks = DUAL ? nchunks1 + 4 : nchunks1;

    for (int c = 0; c < nchunks; c++) {
        const float* A; const short *Bh, *Bl; int kc, K;
        if (!DUAL || c < nchunks1) { A = A1; Bh = B1hi; Bl = B1lo; kc = c * 32; K = K1; }
        else { A = A2; Bh = B2hi; Bl = B2lo; kc = (c - nchunks1) * 32; K = 128; }

        __syncthreads();
        // stage A: thread -> row r=t>>1, 16 floats at kc + (t&1)*16
        {
            int r = t >> 1, h = t & 1;
            int gr = m0 + r; if (gr >= M) gr = M - 1;
            const float* ap = A + (size_t)gr * K + kc + h * 16;
            float f[16];
            *(float4*)&f[0]  = ((const float4*)ap)[0];
            *(float4*)&f[4]  = ((const float4*)ap)[1];
            *(float4*)&f[8]  = ((const float4*)ap)[2];
            *(float4*)&f[12] = ((const float4*)ap)[3];
            bf16x8 h0, l0, h1, l1;
            split8(&f[0], h0, l0);
            split8(&f[8], h1, l1);
            *(bf16x8*)&Ahi[r][h * 16]     = h0;
            *(bf16x8*)&Ahi[r][h * 16 + 8] = h1;
            *(bf16x8*)&Alo[r][h * 16]     = l0;
            *(bf16x8*)&Alo[r][h * 16 + 8] = l1;
        }
        // stage B: thread -> n-row t, 32 shorts at kc
        {
            const float4* bh = (const float4*)(Bh + (size_t)t * K + kc);
            const float4* bl = (const float4*)(Bl + (size_t)t * K + kc);
            float4 u0 = bh[0], u1 = bh[1], u2 = bh[2], u3 = bh[3];
            float4 v0 = bl[0], v1 = bl[1], v2 = bl[2], v3 = bl[3];
            *(float4*)&Bhi[t][0]  = u0; *(float4*)&Bhi[t][8]  = u1;
            *(float4*)&Bhi[t][16] = u2; *(float4*)&Bhi[t][24] = u3;
            *(float4*)&Blo[t][0]  = v0; *(float4*)&Blo[t][8]  = v1;
            *(float4*)&Blo[t][16] = v2; *(float4*)&Blo[t][24] = v3;
        }
        __syncthreads();

        bf16x8 a_hi[2], a_lo[2];
#pragma unroll
        for (int mt = 0; mt < 2; mt++) {
            a_hi[mt] = *(const bf16x8*)&Ahi[w * 32 + mt * 16 + ln][q * 8];
            a_lo[mt] = *(const bf16x8*)&Alo[w * 32 + mt * 16 + ln][q * 8];
        }
#pragma unroll
        for (int nt = 0; nt < 8; nt++) {
            bf16x8 bh = *(const bf16x8*)&Bhi[nt * 16 + ln][q * 8];
            bf16x8 bl = *(const bf16x8*)&Blo[nt * 16 + ln][q * 8];
#pragma unroll
            for (int mt = 0; mt < 2; mt++) {
                acc[mt][nt] = __builtin_amdgcn_mfma_f32_16x16x32_bf16(a_hi[mt], bh, acc[mt][nt], 0, 0, 0);
                acc[mt][nt] = __builtin_amdgcn_mfma_f32_16x16x32_bf16(a_hi[mt], bl, acc[mt][nt], 0, 0, 0);
                acc[mt][nt] = __builtin_amdgcn_mfma_f32_16x16x32_bf16(a_lo[mt], bh, acc[mt][nt], 0, 0, 0);
            }
        }
    }

    // epilogue: col = nt*16+ln, row = m0 + w*32 + mt*16 + q*4 + i
#pragma unroll
    for (int nt = 0; nt < 8; nt++) {
        int col = nt * 16 + ln;
        float bv = bias[col];
#pragma unroll
        for (int mt = 0; mt < 2; mt++) {
            f32x4 v = acc[mt][nt];
#pragma unroll
            for (int i = 0; i < 4; i++) {
                int m = m0 + w * 32 + mt * 16 + q * 4 + i;
                if (m < M) {
                    float x = v[i] + bv;
                    if (ACT) x = lrelu(x);
                    C[(size_t)m * 128 + col] = x;
                }
            }
        }
    }
}

// ---------------- small feature encoders (K=6, K=11) ----------------
__global__ __launch_bounds__(256) void encode_small(const float* __restrict__ num_prop,
                                                    const float* __restrict__ cat_prop,
                                                    const float* __restrict__ W_np,
                                                    const float* __restrict__ b_np,
                                                    const float* __restrict__ W_cp,
                                                    const float* __restrict__ b_cp,
                                                    float* __restrict__ x) {
    int t = blockIdx.x * 256 + threadIdx.x;
    int node = t >> 6;
    int jj = t & 63;
    if (node >= N_NODES) return;
    if (jj < 32) {
        float acc = b_np[jj];
        const float* row = num_prop + (size_t)node * 6;
#pragma unroll
        for (int k = 0; k < 6; k++) acc = fmaf(row[k], W_np[k * 32 + jj], acc);
        x[(size_t)node * 128 + 64 + jj] = lrelu(acc);
    } else {
        int j = jj - 32;
        float acc = b_cp[j];
        const float* row = cat_prop + (size_t)node * 11;
#pragma unroll
        for (int k = 0; k < 11; k++) acc = fmaf(row[k], W_cp[k * 32 + j], acc);
        x[(size_t)node * 128 + 96 + j] = lrelu(acc);
    }
}

// ---------------- K=768 -> 32 encoder GEMM (des / tweet), fp32 ----------------
__global__ __launch_bounds__(256) void gemm_k768_n32(const float* __restrict__ A,
                                                     const float* __restrict__ W,
                                                     const float* __restrict__ bias,
                                                     float* __restrict__ C,
                                                     int M, int colofs) {
    __shared__ float As[128][36];
    __shared__ float Ws[32][33];
    const int t = threadIdx.x;
    const int tj = t & 31, tm = t >> 5;
    const int m0 = blockIdx.x * 128;
    float acc[16];
#pragma unroll
    for (int i = 0; i < 16; i++) acc[i] = 0.f;

    for (int kc = 0; kc < 768; kc += 32) {
#pragma unroll
        for (int i = 0; i < 4; i++) {
            int f4 = t + i * 256;
            int row = f4 >> 3, c4 = f4 & 7;
            int gr = m0 + row; if (gr >= M) gr = M - 1;
            *(float4*)&As[row][c4 * 4] =
                *(const float4*)(A + (size_t)gr * 768 + kc + c4 * 4);
        }
#pragma unroll
        for (int i = 0; i < 4; i++) {
            int idx = t + i * 256;
            int kr = idx >> 5, cc = idx & 31;
            Ws[kr][cc] = W[(size_t)(kc + kr) * 32 + cc];
        }
        __syncthreads();
#pragma unroll
        for (int k = 0; k < 32; k++) {
            float w = Ws[k][tj];
#pragma unroll
            for (int mm = 0; mm < 16; mm++)
                acc[mm] = fmaf(As[tm * 16 + mm][k], w, acc[mm]);
        }
        __syncthreads();
    }
    float b = bias[tj];
#pragma unroll
    for (int mm = 0; mm < 16; mm++) {
        int m = m0 + tm * 16 + mm;
        if (m < M) C[(size_t)m * 128 + colofs + tj] = lrelu(acc[mm] + b);
    }
}

// ---------------- final projection 128 -> 2 ----------------
__global__ __launch_bounds__(256) void out_proj(const float* __restrict__ X,
                                                const float* __restrict__ W,
                                                const float* __restrict__ b,
                                                float* __restrict__ out, int M) {
    int n = blockIdx.x * 256 + threadIdx.x;
    if (n >= M) return;
    float a0 = b[0], a1 = b[1];
    const float4* xr = (const float4*)(X + (size_t)n * 128);
#pragma unroll
    for (int k4 = 0; k4 < 32; k4++) {
        float4 v = xr[k4];
        a0 = fmaf(v.x, W[(k4 * 4 + 0) * 2 + 0], a0);
        a1 = fmaf(v.x, W[(k4 * 4 + 0) * 2 + 1], a1);
        a0 = fmaf(v.y, W[(k4 * 4 + 1) * 2 + 0], a0);
        a1 = fmaf(v.y, W[(k4 * 4 + 1) * 2 + 1], a1);
        a0 = fmaf(v.z, W[(k4 * 4 + 2) * 2 + 0], a0);
        a1 = fmaf(v.z, W[(k4 * 4 + 2) * 2 + 1], a1);
        a0 = fmaf(v.w, W[(k4 * 4 + 3) * 2 + 0], a0);
        a1 = fmaf(v.w, W[(k4 * 4 + 3) * 2 + 1], a1);
    }
    out[(size_t)n * 2 + 0] = a0;
    out[(size_t)n * 2 + 1] = a1;
}

static inline size_t align64(size_t x) { return (x + 63) & ~(size_t)63; }

extern "C" void kernel_launch(void* const* d_in, const int* in_sizes, int n_in,
                              void* d_out, int out_size, void* d_ws, size_t ws_size,
                              hipStream_t stream) {
    const float* des      = (const float*)d_in[0];
    const float* tweet    = (const float*)d_in[1];
    const float* num_prop = (const float*)d_in[2];
    const float* cat_prop = (const float*)d_in[3];
    const int*   edge_index = (const int*)d_in[4];
    const int*   edge_type  = (const int*)d_in[5];
    const float* W_des = (const float*)d_in[6];  const float* b_des = (const float*)d_in[7];
    const float* W_tw  = (const float*)d_in[8];  const float* b_tw  = (const float*)d_in[9];
    const float* W_np  = (const float*)d_in[10]; const float* b_np  = (const float*)d_in[11];
    const float* W_cp  = (const float*)d_in[12]; const float* b_cp  = (const float*)d_in[13];
    const float* W_in  = (const float*)d_in[14]; const float* b_in  = (const float*)d_in[15];
    const float* rel_w = (const float*)d_in[16]; const float* root_w = (const float*)d_in[17];
    const float* rgcn_b = (const float*)d_in[18];
    const float* W_o1  = (const float*)d_in[19]; const float* b_o1  = (const float*)d_in[20];
    const float* W_o2  = (const float*)d_in[21]; const float* b_o2  = (const float*)d_in[22];
    float* out = (float*)d_out;

    // workspace layout
    char* p = (char*)d_ws;
    float* agg = (float*)p;            p += (size_t)NSEG * 128 * 4;
    float* xA  = (float*)p;            p += (size_t)N_NODES * 128 * 4;
    float* xB  = (float*)p;            p += (size_t)N_NODES * 128 * 4;
    int* cnt       = (int*)p;          p += (size_t)NSEG * 4;
    int* rowptr    = (int*)p;          p += (size_t)(NSEG + 1) * 4;
    int* cursor    = (int*)p;          p += (size_t)NSEG * 4;
    int* srcSorted = (int*)p;          p += (size_t)N_EDGES * 4;
    int* blockSums = (int*)p;          p += (size_t)256 * 4;
    p = (char*)align64((size_t)p);
    short* w1hi = (short*)p;           p += (size_t)640 * 128 * 2;
    short* w1lo = (short*)p;           p += (size_t)640 * 128 * 2;
    short* w2hi = (short*)p;           p += (size_t)128 * 128 * 2;
    short* w2lo = (short*)p;           p += (size_t)128 * 128 * 2;
    short* winhi = (short*)p;          p += (size_t)128 * 128 * 2;
    short* winlo = (short*)p;          p += (size_t)128 * 128 * 2;
    short* wo1hi = (short*)p;          p += (size_t)128 * 128 * 2;
    short* wo1lo = (short*)p;          p += (size_t)128 * 128 * 2;

    // 0. weight prep (split + transpose to n-major bf16 planes)
    split_transpose<<<(640 * 128 + 255) / 256, 256, 0, stream>>>(rel_w, w1hi, w1lo, 640);
    split_transpose<<<(128 * 128 + 255) / 256, 256, 0, stream>>>(root_w, w2hi, w2lo, 128);
    split_transpose<<<(128 * 128 + 255) / 256, 256, 0, stream>>>(W_in, winhi, winlo, 128);
    split_transpose<<<(128 * 128 + 255) / 256, 256, 0, stream>>>(W_o1, wo1hi, wo1lo, 128);

    // 1. CSR build (layer-invariant)
    hipMemsetAsync(cnt, 0, (size_t)NSEG * sizeof(int), stream);
    hipMemsetAsync(cursor, 0, (size_t)NSEG * sizeof(int), stream);
    count_kernel<<<(N_EDGES + 255) / 256, 256, 0, stream>>>(edge_index, edge_type, cnt);
    scan1<<<SCAN_NB, SCAN_BS, 0, stream>>>(cnt, rowptr, blockSums);
    scan2<<<1, 256, 0, stream>>>(blockSums);
    scan3<<<SCAN_NB, SCAN_BS, 0, stream>>>(rowptr, blockSums);
    fill_kernel<<<(N_EDGES + 255) / 256, 256, 0, stream>>>(
        edge_index, edge_type, rowptr, cursor, srcSorted);

    // 2. encode
    encode_small<<<(N_NODES * 64 + 255) / 256, 256, 0, stream>>>(
        num_prop, cat_prop, W_np, b_np, W_cp, b_cp, xA);
    gemm_k768_n32<<<(N_NODES + 127) / 128, 256, 0, stream>>>(des, W_des, b_des, xA, N_NODES, 0);
    gemm_k768_n32<<<(N_NODES + 127) / 128, 256, 0, stream>>>(tweet, W_tw, b_tw, xA, N_NODES, 32);

    // 3. input linear (MFMA)
    mfma_gemm<true, false><<<(N_NODES + 63) / 64, 128, 0, stream>>>(
        xA, 128, winhi, winlo, nullptr, nullptr, nullptr, b_in, xB, N_NODES);

    // 4. RGCN x4
    float* cur = xB; float* nxt = xA;
    for (int l = 0; l < 4; l++) {
        agg_kernel<<<(NSEG * 64 + 255) / 256, 256, 0, stream>>>(cur, srcSorted, rowptr, agg);
        mfma_gemm<false, true><<<(N_NODES + 63) / 64, 128, 0, stream>>>(
            agg, 640, w1hi, w1lo, cur, w2hi, w2lo, rgcn_b, nxt, N_NODES);
        float* tmp = cur; cur = nxt; nxt = tmp;
    }

    // 5. output head
    mfma_gemm<true, false><<<(N_NODES + 63) / 64, 128, 0, stream>>>(
        cur, 128, wo1hi, wo1lo, nullptr, nullptr, nullptr, b_o1, nxt, N_NODES);
    out_proj<<<(N_NODES + 255) / 256, 256, 0, stream>>>(nxt, W_o2, b_o2, out, N_NODES);
}

// Round 4
// 1351.304 us; speedup vs baseline: 4.9333x; 1.0478x over previous
//
#include <hip/hip_runtime.h>

// BotRGCN 4-layer forward.
// Round 4: (1) encoder GEMMs -> MFMA bf16x3; (2) mfma_gemm B-fragments loaded
// direct from global (no B LDS round-trip); (3) agg_kernel float4, 32 lanes/seg.

#define N_NODES 50000
#define N_EDGES 800000
#define R_REL   5
#define NSEG    (N_NODES * R_REL)   // 250000
#define SCAN_BS 1024
#define SCAN_NB ((NSEG + SCAN_BS - 1) / SCAN_BS)   // 245

typedef __attribute__((ext_vector_type(8))) short bf16x8;
typedef __attribute__((ext_vector_type(4))) float f32x4;

__device__ __forceinline__ float lrelu(float v) { return v > 0.f ? v : 0.01f * v; }

__device__ __forceinline__ unsigned short f2bf_rne(float f) {
    unsigned u = __float_as_uint(f);
    return (unsigned short)((u + 0x7fff + ((u >> 16) & 1)) >> 16);
}

// split 8 consecutive floats into bf16 hi (truncation) + lo (RNE of residual)
__device__ __forceinline__ void split8(const float* f, bf16x8& hi, bf16x8& lo) {
#pragma unroll
    for (int i = 0; i < 8; i++) {
        unsigned u = __float_as_uint(f[i]);
        unsigned short h = (unsigned short)(u >> 16);
        float hf = __uint_as_float((unsigned)h << 16);
        float l = f[i] - hf;
        hi[i] = (short)h;
        lo[i] = (short)f2bf_rne(l);
    }
}

// ---------------- CSR build ----------------
__global__ __launch_bounds__(256) void count_kernel(const int* __restrict__ ei,
                                                    const int* __restrict__ et,
                                                    int* __restrict__ cnt) {
    int e = blockIdx.x * 256 + threadIdx.x;
    if (e >= N_EDGES) return;
    atomicAdd(&cnt[ei[N_EDGES + e] * R_REL + et[e]], 1);
}

__global__ __launch_bounds__(SCAN_BS) void scan1(const int* __restrict__ cnt,
                                                 int* __restrict__ rowptr,
                                                 int* __restrict__ blockSums) {
    __shared__ int s[SCAN_BS];
    int t = threadIdx.x;
    int i = blockIdx.x * SCAN_BS + t;
    int v = (i < NSEG) ? cnt[i] : 0;
    s[t] = v;
    __syncthreads();
#pragma unroll
    for (int off = 1; off < SCAN_BS; off <<= 1) {
        int add = (t >= off) ? s[t - off] : 0;
        __syncthreads();
        s[t] += add;
        __syncthreads();
    }
    if (i < NSEG) rowptr[i] = s[t] - v;
    if (t == SCAN_BS - 1) blockSums[blockIdx.x] = s[t];
}

__global__ __launch_bounds__(256) void scan2(int* __restrict__ blockSums) {
    __shared__ int s[256];
    int t = threadIdx.x;
    int v = (t < SCAN_NB) ? blockSums[t] : 0;
    s[t] = v;
    __syncthreads();
#pragma unroll
    for (int off = 1; off < 256; off <<= 1) {
        int add = (t >= off) ? s[t - off] : 0;
        __syncthreads();
        s[t] += add;
        __syncthreads();
    }
    if (t < SCAN_NB) blockSums[t] = s[t] - v;
}

__global__ __launch_bounds__(SCAN_BS) void scan3(int* __restrict__ rowptr,
                                                 const int* __restrict__ blockSums) {
    int i = blockIdx.x * SCAN_BS + threadIdx.x;
    if (i == 0) rowptr[NSEG] = N_EDGES;
    if (i < NSEG) rowptr[i] += blockSums[blockIdx.x];
}

__global__ __launch_bounds__(256) void fill_kernel(const int* __restrict__ ei,
                                                   const int* __restrict__ et,
                                                   const int* __restrict__ rowptr,
                                                   int* __restrict__ cursor,
                                                   int* __restrict__ srcSorted) {
    int e = blockIdx.x * 256 + threadIdx.x;
    if (e >= N_EDGES) return;
    int seg = ei[N_EDGES + e] * R_REL + et[e];
    int pos = atomicAdd(&cursor[seg], 1);
    srcSorted[rowptr[seg] + pos] = ei[e];
}

// ---------------- gather-reduce aggregation: 32 lanes/seg, float4 ----------------
__global__ __launch_bounds__(256) void agg_kernel(const float* __restrict__ x,
                                                  const int* __restrict__ srcSorted,
                                                  const int* __restrict__ rowptr,
                                                  float* __restrict__ agg) {
    int t = blockIdx.x * 256 + threadIdx.x;
    int seg = t >> 5;
    if (seg >= NSEG) return;
    int lane = t & 31;
    int beg = rowptr[seg], end = rowptr[seg + 1];
    float ax = 0.f, ay = 0.f, az = 0.f, aw = 0.f;
    for (int i = beg; i < end; i++) {
        int src = srcSorted[i];
        float4 v = ((const float4*)(x + (size_t)src * 128))[lane];
        ax += v.x; ay += v.y; az += v.z; aw += v.w;
    }
    int c = end - beg;
    float s = 1.0f / (float)(c > 1 ? c : 1);
    *(float4*)(agg + (size_t)seg * 128 + lane * 4) =
        make_float4(ax * s, ay * s, az * s, aw * s);
}

// ---------------- weight prep: fp32 [K][NC] -> bf16 hi/lo transposed [NC][K] ----------------
__global__ __launch_bounds__(256) void split_transpose(const float* __restrict__ W,
                                                       short* __restrict__ Whi,
                                                       short* __restrict__ Wlo,
                                                       int K, int NC) {
    int idx = blockIdx.x * 256 + threadIdx.x;
    if (idx >= K * NC) return;
    int k = idx / NC, n = idx % NC;
    float w = W[idx];
    unsigned u = __float_as_uint(w);
    unsigned short h = (unsigned short)(u >> 16);
    float hf = __uint_as_float((unsigned)h << 16);
    unsigned short l = f2bf_rne(w - hf);
    Whi[(size_t)n * K + k] = (short)h;
    Wlo[(size_t)n * K + k] = (short)l;
}

// ---------------- MFMA bf16x3 GEMM, N=128 outputs ----------------
// C[M,128] = act( A1[M,K1]@W1 (+ A2[M,128]@W2) + bias )
// B planes n-major bf16: B[n][k]; fragments loaded direct from global (L2-hot).
// Block: 128 threads (2 waves), 64 rows.
template <bool ACT, bool DUAL>
__global__ __launch_bounds__(128) void mfma_gemm(const float* __restrict__ A1, int K1,
                                                 const short* __restrict__ B1hi,
                                                 const short* __restrict__ B1lo,
                                                 const float* __restrict__ A2,
                                                 const short* __restrict__ B2hi,
                                                 const short* __restrict__ B2lo,
                                                 const float* __restrict__ bias,
                                                 float* __restrict__ C, int M) {
    __shared__ short Ahi[64][40], Alo[64][40];
    const int t = threadIdx.x;
    const int m0 = blockIdx.x * 64;
    const int w = t >> 6, lane = t & 63;
    const int q = lane >> 4, ln = lane & 15;

    f32x4 acc[2][8];
#pragma unroll
    for (int mt = 0; mt < 2; mt++)
#pragma unroll
        for (int nt = 0; nt < 8; nt++) acc[mt][nt] = (f32x4)0.f;

    const int nchunks1 = K1 / 32;
    const int nchunks = DUAL ? nchunks1 + 4 : nchunks1;

    for (int c = 0; c < nchunks; c++) {
        const float* A; const short *Bh, *Bl; int kc, K;
        if (!DUAL || c < nchunks1) { A = A1; Bh = B1hi; Bl = B1lo; kc = c * 32; K = K1; }
        else { A = A2; Bh = B2hi; Bl = B2lo; kc = (c - nchunks1) * 32; K = 128; }

        __syncthreads();
        // stage A: thread -> row r=t>>1, 16 floats at kc + (t&1)*16
        {
            int r = t >> 1, h = t & 1;
            int gr = m0 + r; if (gr >= M) gr = M - 1;
            const float* ap = A + (size_t)gr * K + kc + h * 16;
            float f[16];
            *(float4*)&f[0]  = ((const float4*)ap)[0];
            *(float4*)&f[4]  = ((const float4*)ap)[1];
            *(float4*)&f[8]  = ((const float4*)ap)[2];
            *(float4*)&f[12] = ((const float4*)ap)[3];
            bf16x8 h0, l0, h1, l1;
            split8(&f[0], h0, l0);
            split8(&f[8], h1, l1);
            *(bf16x8*)&Ahi[r][h * 16]     = h0;
            *(bf16x8*)&Ahi[r][h * 16 + 8] = h1;
            *(bf16x8*)&Alo[r][h * 16]     = l0;
            *(bf16x8*)&Alo[r][h * 16 + 8] = l1;
        }
        __syncthreads();

        bf16x8 a_hi[2], a_lo[2];
#pragma unroll
        for (int mt = 0; mt < 2; mt++) {
            a_hi[mt] = *(const bf16x8*)&Ahi[w * 32 + mt * 16 + ln][q * 8];
            a_lo[mt] = *(const bf16x8*)&Alo[w * 32 + mt * 16 + ln][q * 8];
        }
#pragma unroll
        for (int nt = 0; nt < 8; nt++) {
            const size_t bofs = (size_t)(nt * 16 + ln) * K + kc + q * 8;
            bf16x8 bh = *(const bf16x8*)(Bh + bofs);
            bf16x8 bl = *(const bf16x8*)(Bl + bofs);
#pragma unroll
            for (int mt = 0; mt < 2; mt++) {
                acc[mt][nt] = __builtin_amdgcn_mfma_f32_16x16x32_bf16(a_hi[mt], bh, acc[mt][nt], 0, 0, 0);
                acc[mt][nt] = __builtin_amdgcn_mfma_f32_16x16x32_bf16(a_hi[mt], bl, acc[mt][nt], 0, 0, 0);
                acc[mt][nt] = __builtin_amdgcn_mfma_f32_16x16x32_bf16(a_lo[mt], bh, acc[mt][nt], 0, 0, 0);
            }
        }
    }

    // epilogue: col = nt*16+ln, row = m0 + w*32 + mt*16 + q*4 + i
#pragma unroll
    for (int nt = 0; nt < 8; nt++) {
        int col = nt * 16 + ln;
        float bv = bias[col];
#pragma unroll
        for (int mt = 0; mt < 2; mt++) {
            f32x4 v = acc[mt][nt];
#pragma unroll
            for (int i = 0; i < 4; i++) {
                int m = m0 + w * 32 + mt * 16 + q * 4 + i;
                if (m < M) {
                    float x = v[i] + bv;
                    if (ACT) x = lrelu(x);
                    C[(size_t)m * 128 + col] = x;
                }
            }
        }
    }
}

// ---------------- MFMA bf16x3 encoder GEMM: K=768 -> 32 cols ----------------
// C[m, colofs + j] = lrelu(A[m,:]@W[:,j] + b[j]); C row stride 128.
// Block: 256 threads (4 waves), 128 rows. B planes [32][768] n-major, direct global.
__global__ __launch_bounds__(256) void mfma_enc32(const float* __restrict__ A,
                                                  const short* __restrict__ Bhi_g,
                                                  const short* __restrict__ Blo_g,
                                                  const float* __restrict__ bias,
                                                  float* __restrict__ C,
                                                  int M, int colofs) {
    __shared__ short Ahi[128][40], Alo[128][40];
    const int t = threadIdx.x;
    const int m0 = blockIdx.x * 128;
    const int w = t >> 6, lane = t & 63;
    const int q = lane >> 4, ln = lane & 15;
    const int K = 768;

    f32x4 acc[2][2];
#pragma unroll
    for (int mt = 0; mt < 2; mt++)
#pragma unroll
        for (int nt = 0; nt < 2; nt++) acc[mt][nt] = (f32x4)0.f;

    for (int c = 0; c < 24; c++) {
        int kc = c * 32;
        __syncthreads();
        {
            int r = t >> 1, h = t & 1;
            int gr = m0 + r; if (gr >= M) gr = M - 1;
            const float* ap = A + (size_t)gr * K + kc + h * 16;
            float f[16];
            *(float4*)&f[0]  = ((const float4*)ap)[0];
            *(float4*)&f[4]  = ((const float4*)ap)[1];
            *(float4*)&f[8]  = ((const float4*)ap)[2];
            *(float4*)&f[12] = ((const float4*)ap)[3];
            bf16x8 h0, l0, h1, l1;
            split8(&f[0], h0, l0);
            split8(&f[8], h1, l1);
            *(bf16x8*)&Ahi[r][h * 16]     = h0;
            *(bf16x8*)&Ahi[r][h * 16 + 8] = h1;
            *(bf16x8*)&Alo[r][h * 16]     = l0;
            *(bf16x8*)&Alo[r][h * 16 + 8] = l1;
        }
        __syncthreads();

        bf16x8 a_hi[2], a_lo[2];
#pragma unroll
        for (int mt = 0; mt < 2; mt++) {
            a_hi[mt] = *(const bf16x8*)&Ahi[w * 32 + mt * 16 + ln][q * 8];
            a_lo[mt] = *(const bf16x8*)&Alo[w * 32 + mt * 16 + ln][q * 8];
        }
#pragma unroll
        for (int nt = 0; nt < 2; nt++) {
            const size_t bofs = (size_t)(nt * 16 + ln) * K + kc + q * 8;
            bf16x8 bh = *(const bf16x8*)(Bhi_g + bofs);
            bf16x8 bl = *(const bf16x8*)(Blo_g + bofs);
#pragma unroll
            for (int mt = 0; mt < 2; mt++) {
                acc[mt][nt] = __builtin_amdgcn_mfma_f32_16x16x32_bf16(a_hi[mt], bh, acc[mt][nt], 0, 0, 0);
                acc[mt][nt] = __builtin_amdgcn_mfma_f32_16x16x32_bf16(a_hi[mt], bl, acc[mt][nt], 0, 0, 0);
                acc[mt][nt] = __builtin_amdgcn_mfma_f32_16x16x32_bf16(a_lo[mt], bh, acc[mt][nt], 0, 0, 0);
            }
        }
    }

#pragma unroll
    for (int nt = 0; nt < 2; nt++) {
        int col = nt * 16 + ln;
        float bv = bias[col];
#pragma unroll
        for (int mt = 0; mt < 2; mt++) {
            f32x4 v = acc[mt][nt];
#pragma unroll
            for (int i = 0; i < 4; i++) {
                int m = m0 + w * 32 + mt * 16 + q * 4 + i;
                if (m < M)
                    C[(size_t)m * 128 + colofs + col] = lrelu(v[i] + bv);
            }
        }
    }
}

// ---------------- small feature encoders (K=6, K=11) ----------------
__global__ __launch_bounds__(256) void encode_small(const float* __restrict__ num_prop,
                                                    const float* __restrict__ cat_prop,
                                                    const float* __restrict__ W_np,
                                                    const float* __restrict__ b_np,
                                                    const float* __restrict__ W_cp,
                                                    const float* __restrict__ b_cp,
                                                    float* __restrict__ x) {
    int t = blockIdx.x * 256 + threadIdx.x;
    int node = t >> 6;
    int jj = t & 63;
    if (node >= N_NODES) return;
    if (jj < 32) {
        float acc = b_np[jj];
        const float* row = num_prop + (size_t)node * 6;
#pragma unroll
        for (int k = 0; k < 6; k++) acc = fmaf(row[k], W_np[k * 32 + jj], acc);
        x[(size_t)node * 128 + 64 + jj] = lrelu(acc);
    } else {
        int j = jj - 32;
        float acc = b_cp[j];
        const float* row = cat_prop + (size_t)node * 11;
#pragma unroll
        for (int k = 0; k < 11; k++) acc = fmaf(row[k], W_cp[k * 32 + j], acc);
        x[(size_t)node * 128 + 96 + j] = lrelu(acc);
    }
}

// ---------------- final projection 128 -> 2 ----------------
__global__ __launch_bounds__(256) void out_proj(const float* __restrict__ X,
                                                const float* __restrict__ W,
                                                const float* __restrict__ b,
                                                float* __restrict__ out, int M) {
    int n = blockIdx.x * 256 + threadIdx.x;
    if (n >= M) return;
    float a0 = b[0], a1 = b[1];
    const float4* xr = (const float4*)(X + (size_t)n * 128);
#pragma unroll
    for (int k4 = 0; k4 < 32; k4++) {
        float4 v = xr[k4];
        a0 = fmaf(v.x, W[(k4 * 4 + 0) * 2 + 0], a0);
        a1 = fmaf(v.x, W[(k4 * 4 + 0) * 2 + 1], a1);
        a0 = fmaf(v.y, W[(k4 * 4 + 1) * 2 + 0], a0);
        a1 = fmaf(v.y, W[(k4 * 4 + 1) * 2 + 1], a1);
        a0 = fmaf(v.z, W[(k4 * 4 + 2) * 2 + 0], a0);
        a1 = fmaf(v.z, W[(k4 * 4 + 2) * 2 + 1], a1);
        a0 = fmaf(v.w, W[(k4 * 4 + 3) * 2 + 0], a0);
        a1 = fmaf(v.w, W[(k4 * 4 + 3) * 2 + 1], a1);
    }
    out[(size_t)n * 2 + 0] = a0;
    out[(size_t)n * 2 + 1] = a1;
}

static inline size_t align64(size_t x) { return (x + 63) & ~(size_t)63; }

extern "C" void kernel_launch(void* const* d_in, const int* in_sizes, int n_in,
                              void* d_out, int out_size, void* d_ws, size_t ws_size,
                              hipStream_t stream) {
    const float* des      = (const float*)d_in[0];
    const float* tweet    = (const float*)d_in[1];
    const float* num_prop = (const float*)d_in[2];
    const float* cat_prop = (const float*)d_in[3];
    const int*   edge_index = (const int*)d_in[4];
    const int*   edge_type  = (const int*)d_in[5];
    const float* W_des = (const float*)d_in[6];  const float* b_des = (const float*)d_in[7];
    const float* W_tw  = (const float*)d_in[8];  const float* b_tw  = (const float*)d_in[9];
    const float* W_np  = (const float*)d_in[10]; const float* b_np  = (const float*)d_in[11];
    const float* W_cp  = (const float*)d_in[12]; const float* b_cp  = (const float*)d_in[13];
    const float* W_in  = (const float*)d_in[14]; const float* b_in  = (const float*)d_in[15];
    const float* rel_w = (const float*)d_in[16]; const float* root_w = (const float*)d_in[17];
    const float* rgcn_b = (const float*)d_in[18];
    const float* W_o1  = (const float*)d_in[19]; const float* b_o1  = (const float*)d_in[20];
    const float* W_o2  = (const float*)d_in[21]; const float* b_o2  = (const float*)d_in[22];
    float* out = (float*)d_out;

    // workspace layout
    char* p = (char*)d_ws;
    float* agg = (float*)p;            p += (size_t)NSEG * 128 * 4;
    float* xA  = (float*)p;            p += (size_t)N_NODES * 128 * 4;
    float* xB  = (float*)p;            p += (size_t)N_NODES * 128 * 4;
    int* cnt       = (int*)p;          p += (size_t)NSEG * 4;
    int* rowptr    = (int*)p;          p += (size_t)(NSEG + 1) * 4;
    int* cursor    = (int*)p;          p += (size_t)NSEG * 4;
    int* srcSorted = (int*)p;          p += (size_t)N_EDGES * 4;
    int* blockSums = (int*)p;          p += (size_t)256 * 4;
    p = (char*)align64((size_t)p);
    short* w1hi = (short*)p;           p += (size_t)640 * 128 * 2;
    short* w1lo = (short*)p;           p += (size_t)640 * 128 * 2;
    short* w2hi = (short*)p;           p += (size_t)128 * 128 * 2;
    short* w2lo = (short*)p;           p += (size_t)128 * 128 * 2;
    short* winhi = (short*)p;          p += (size_t)128 * 128 * 2;
    short* winlo = (short*)p;          p += (size_t)128 * 128 * 2;
    short* wo1hi = (short*)p;          p += (size_t)128 * 128 * 2;
    short* wo1lo = (short*)p;          p += (size_t)128 * 128 * 2;
    short* wdhi = (short*)p;           p += (size_t)768 * 32 * 2;
    short* wdlo = (short*)p;           p += (size_t)768 * 32 * 2;
    short* wthi = (short*)p;           p += (size_t)768 * 32 * 2;
    short* wtlo = (short*)p;           p += (size_t)768 * 32 * 2;

    // 0. weight prep (split + transpose to n-major bf16 planes)
    split_transpose<<<(640 * 128 + 255) / 256, 256, 0, stream>>>(rel_w, w1hi, w1lo, 640, 128);
    split_transpose<<<(128 * 128 + 255) / 256, 256, 0, stream>>>(root_w, w2hi, w2lo, 128, 128);
    split_transpose<<<(128 * 128 + 255) / 256, 256, 0, stream>>>(W_in, winhi, winlo, 128, 128);
    split_transpose<<<(128 * 128 + 255) / 256, 256, 0, stream>>>(W_o1, wo1hi, wo1lo, 128, 128);
    split_transpose<<<(768 * 32 + 255) / 256, 256, 0, stream>>>(W_des, wdhi, wdlo, 768, 32);
    split_transpose<<<(768 * 32 + 255) / 256, 256, 0, stream>>>(W_tw, wthi, wtlo, 768, 32);

    // 1. CSR build (layer-invariant)
    hipMemsetAsync(cnt, 0, (size_t)NSEG * sizeof(int), stream);
    hipMemsetAsync(cursor, 0, (size_t)NSEG * sizeof(int), stream);
    count_kernel<<<(N_EDGES + 255) / 256, 256, 0, stream>>>(edge_index, edge_type, cnt);
    scan1<<<SCAN_NB, SCAN_BS, 0, stream>>>(cnt, rowptr, blockSums);
    scan2<<<1, 256, 0, stream>>>(blockSums);
    scan3<<<SCAN_NB, SCAN_BS, 0, stream>>>(rowptr, blockSums);
    fill_kernel<<<(N_EDGES + 255) / 256, 256, 0, stream>>>(
        edge_index, edge_type, rowptr, cursor, srcSorted);

    // 2. encode
    encode_small<<<(N_NODES * 64 + 255) / 256, 256, 0, stream>>>(
        num_prop, cat_prop, W_np, b_np, W_cp, b_cp, xA);
    mfma_enc32<<<(N_NODES + 127) / 128, 256, 0, stream>>>(des, wdhi, wdlo, b_des, xA, N_NODES, 0);
    mfma_enc32<<<(N_NODES + 127) / 128, 256, 0, stream>>>(tweet, wthi, wtlo, b_tw, xA, N_NODES, 32);

    // 3. input linear (MFMA)
    mfma_gemm<true, false><<<(N_NODES + 63) / 64, 128, 0, stream>>>(
        xA, 128, winhi, winlo, nullptr, nullptr, nullptr, b_in, xB, N_NODES);

    // 4. RGCN x4
    float* cur = xB; float* nxt = xA;
    for (int l = 0; l < 4; l++) {
        agg_kernel<<<(NSEG * 32 + 255) / 256, 256, 0, stream>>>(cur, srcSorted, rowptr, agg);
        mfma_gemm<false, true><<<(N_NODES + 63) / 64, 128, 0, stream>>>(
            agg, 640, w1hi, w1lo, cur, w2hi, w2lo, rgcn_b, nxt, N_NODES);
        float* tmp = cur; cur = nxt; nxt = tmp;
    }

    // 5. output head
    mfma_gemm<true, false><<<(N_NODES + 63) / 64, 128, 0, stream>>>(
        cur, 128, wo1hi, wo1lo, nullptr, nullptr, nullptr, b_o1, nxt, N_NODES);
    out_proj<<<(N_NODES + 255) / 256, 256, 0, stream>>>(nxt, W_o2, b_o2, out, N_NODES);
}

// Round 5
// 1031.449 us; speedup vs baseline: 6.4631x; 1.3101x over previous
//
#include <hip/hip_runtime.h>

// BotRGCN 4-layer forward.
// Round 5: GEMM restructure — B pre-swizzled to MFMA fragment order in global
// (coalesced stage), fragment-major A/B LDS layouts (0 bank conflicts),
// 4-wave blocks with 2 m-tiles x NT/2 n-tiles per wave (38% occupancy).

#define N_NODES 50000
#define N_EDGES 800000
#define R_REL   5
#define NSEG    (N_NODES * R_REL)   // 250000
#define SCAN_BS 1024
#define SCAN_NB ((NSEG + SCAN_BS - 1) / SCAN_BS)   // 245

typedef __attribute__((ext_vector_type(8))) short bf16x8;
typedef __attribute__((ext_vector_type(4))) float f32x4;

__device__ __forceinline__ float lrelu(float v) { return v > 0.f ? v : 0.01f * v; }

__device__ __forceinline__ unsigned short f2bf_rne(float f) {
    unsigned u = __float_as_uint(f);
    return (unsigned short)((u + 0x7fff + ((u >> 16) & 1)) >> 16);
}

// split 8 floats into bf16 hi (trunc) + lo (RNE of residual)
__device__ __forceinline__ void split8(const float* f, bf16x8& hi, bf16x8& lo) {
#pragma unroll
    for (int i = 0; i < 8; i++) {
        unsigned u = __float_as_uint(f[i]);
        unsigned short h = (unsigned short)(u >> 16);
        float hf = __uint_as_float((unsigned)h << 16);
        float l = f[i] - hf;
        hi[i] = (short)h;
        lo[i] = (short)f2bf_rne(l);
    }
}

// ---------------- CSR build ----------------
__global__ __launch_bounds__(256) void count_kernel(const int* __restrict__ ei,
                                                    const int* __restrict__ et,
                                                    int* __restrict__ cnt) {
    int e = blockIdx.x * 256 + threadIdx.x;
    if (e >= N_EDGES) return;
    atomicAdd(&cnt[ei[N_EDGES + e] * R_REL + et[e]], 1);
}

__global__ __launch_bounds__(SCAN_BS) void scan1(const int* __restrict__ cnt,
                                                 int* __restrict__ rowptr,
                                                 int* __restrict__ blockSums) {
    __shared__ int s[SCAN_BS];
    int t = threadIdx.x;
    int i = blockIdx.x * SCAN_BS + t;
    int v = (i < NSEG) ? cnt[i] : 0;
    s[t] = v;
    __syncthreads();
#pragma unroll
    for (int off = 1; off < SCAN_BS; off <<= 1) {
        int add = (t >= off) ? s[t - off] : 0;
        __syncthreads();
        s[t] += add;
        __syncthreads();
    }
    if (i < NSEG) rowptr[i] = s[t] - v;
    if (t == SCAN_BS - 1) blockSums[blockIdx.x] = s[t];
}

__global__ __launch_bounds__(256) void scan2(int* __restrict__ blockSums) {
    __shared__ int s[256];
    int t = threadIdx.x;
    int v = (t < SCAN_NB) ? blockSums[t] : 0;
    s[t] = v;
    __syncthreads();
#pragma unroll
    for (int off = 1; off < 256; off <<= 1) {
        int add = (t >= off) ? s[t - off] : 0;
        __syncthreads();
        s[t] += add;
        __syncthreads();
    }
    if (t < SCAN_NB) blockSums[t] = s[t] - v;
}

__global__ __launch_bounds__(SCAN_BS) void scan3(int* __restrict__ rowptr,
                                                 const int* __restrict__ blockSums) {
    int i = blockIdx.x * SCAN_BS + threadIdx.x;
    if (i == 0) rowptr[NSEG] = N_EDGES;
    if (i < NSEG) rowptr[i] += blockSums[blockIdx.x];
}

__global__ __launch_bounds__(256) void fill_kernel(const int* __restrict__ ei,
                                                   const int* __restrict__ et,
                                                   const int* __restrict__ rowptr,
                                                   int* __restrict__ cursor,
                                                   int* __restrict__ srcSorted) {
    int e = blockIdx.x * 256 + threadIdx.x;
    if (e >= N_EDGES) return;
    int seg = ei[N_EDGES + e] * R_REL + et[e];
    int pos = atomicAdd(&cursor[seg], 1);
    srcSorted[rowptr[seg] + pos] = ei[e];
}

// ---------------- gather-reduce aggregation: 32 lanes/seg, float4 ----------------
__global__ __launch_bounds__(256) void agg_kernel(const float* __restrict__ x,
                                                  const int* __restrict__ srcSorted,
                                                  const int* __restrict__ rowptr,
                                                  float* __restrict__ agg) {
    int t = blockIdx.x * 256 + threadIdx.x;
    int seg = t >> 5;
    if (seg >= NSEG) return;
    int lane = t & 31;
    int beg = rowptr[seg], end = rowptr[seg + 1];
    float ax = 0.f, ay = 0.f, az = 0.f, aw = 0.f;
    for (int i = beg; i < end; i++) {
        int src = srcSorted[i];
        float4 v = ((const float4*)(x + (size_t)src * 128))[lane];
        ax += v.x; ay += v.y; az += v.z; aw += v.w;
    }
    int c = end - beg;
    float s = 1.0f / (float)(c > 1 ? c : 1);
    *(float4*)(agg + (size_t)seg * 128 + lane * 4) =
        make_float4(ax * s, ay * s, az * s, aw * s);
}

// ---------------- weight prep: fp32 W[K][NC] (k-major) -> swizzled fragments ----------------
// out layout: [chunk][plane(hi=0,lo=1)][nt][lane(64)][8]  (shorts)
// fragment value for (c, nt, lane l, j): W[k= c*32 + (l>>4)*8 + j][n= nt*16 + (l&15)]
__global__ __launch_bounds__(256) void build_bswz(const float* __restrict__ W,
                                                  int K, int NC, int NTILES,
                                                  short* __restrict__ out) {
    int tid = blockIdx.x * 256 + threadIdx.x;
    int total = (K / 32) * NTILES * 64;
    if (tid >= total) return;
    int l  = tid & 63;
    int nt = (tid >> 6) % NTILES;
    int c  = tid / (64 * NTILES);
    int n = nt * 16 + (l & 15);
    int k0 = c * 32 + (l >> 4) * 8;
    float f[8];
#pragma unroll
    for (int j = 0; j < 8; j++) f[j] = W[(size_t)(k0 + j) * NC + n];
    bf16x8 hi, lo;
    split8(f, hi, lo);
    size_t base = (size_t)c * (2 * NTILES * 512);
    *(bf16x8*)(out + base + ((size_t)nt * 64 + l) * 8) = hi;
    *(bf16x8*)(out + base + (size_t)NTILES * 512 + ((size_t)nt * 64 + l) * 8) = lo;
}

// ---------------- MFMA bf16x3 GEMM ----------------
// C[M, colofs..colofs+NT*16) = act( A1[M,K1]@B1 (+ A2[M,128]@B2) + bias ), C row stride 128.
// Bswz: swizzled fragments, DUAL = concat chunks of B1 (K1/32) then B2 (4).
// Block: 256 threads / 4 waves / 64 rows. Wave (mw,nw): m-tiles {mw*2,mw*2+1},
// n-tiles {nw*NT/2 .. +NT/2-1}.
template <int NT, bool DUAL, bool ACT>
__global__ __launch_bounds__(256) void mfma_gemm(const float* __restrict__ A1, int K1,
                                                 const float* __restrict__ A2,
                                                 const short* __restrict__ Bswz,
                                                 const float* __restrict__ bias,
                                                 float* __restrict__ C, int M,
                                                 int colofs) {
    constexpr int NH = NT / 2;
    __shared__ short Ahi[2048], Alo[2048];      // 4 tiles x (16 rows x 32 k), frag-major
    __shared__ short Bs[NT * 1024];             // [plane][nt][lane][8]
    const int t = threadIdx.x;
    const int m0 = blockIdx.x * 64;
    const int w = t >> 6, l = t & 63;
    const int q = l >> 4, ln = l & 15;
    const int mw = w >> 1, nw = w & 1;

    f32x4 acc[2][NH];
#pragma unroll
    for (int mt = 0; mt < 2; mt++)
#pragma unroll
        for (int nt = 0; nt < NH; nt++) acc[mt][nt] = (f32x4)0.f;

    const int nchunks1 = K1 / 32;
    const int nchunks = DUAL ? nchunks1 + 4 : nchunks1;

    // staging role: row r = t>>2, k-quarter qq = t&3
    const int r = t >> 2, qq = t & 3;
    const int aidx = (r >> 4) * 512 + qq * 128 + (r & 15) * 8;

    for (int c = 0; c < nchunks; c++) {
        const float* A; int kc, K;
        if (!DUAL || c < nchunks1) { A = A1; kc = c * 32; K = K1; }
        else { A = A2; kc = (c - nchunks1) * 32; K = 128; }

        __syncthreads();
        // stage A (fragment-major)
        {
            int gr = m0 + r; if (gr >= M) gr = M - 1;
            const float* ap = A + (size_t)gr * K + kc + qq * 8;
            float f[8];
            *(float4*)&f[0] = ((const float4*)ap)[0];
            *(float4*)&f[4] = ((const float4*)ap)[1];
            bf16x8 h0, l0;
            split8(f, h0, l0);
            *(bf16x8*)&Ahi[aidx] = h0;
            *(bf16x8*)&Alo[aidx] = l0;
        }
        // stage B: flat coalesced copy of NT*1024 shorts
        {
            const short* gb = Bswz + (size_t)c * (NT * 1024);
#pragma unroll
            for (int i = 0; i < NH; i++) {
                int idx = i * 256 + t;
                *(bf16x8*)&Bs[idx * 8] = *(const bf16x8*)(gb + (size_t)idx * 8);
            }
        }
        __syncthreads();

        bf16x8 a_hi[2], a_lo[2];
#pragma unroll
        for (int mt = 0; mt < 2; mt++) {
            a_hi[mt] = *(const bf16x8*)&Ahi[(mw * 2 + mt) * 512 + l * 8];
            a_lo[mt] = *(const bf16x8*)&Alo[(mw * 2 + mt) * 512 + l * 8];
        }
#pragma unroll
        for (int nt = 0; nt < NH; nt++) {
            int ng = nw * NH + nt;
            bf16x8 bh = *(const bf16x8*)&Bs[(ng * 64 + l) * 8];
            bf16x8 bl = *(const bf16x8*)&Bs[NT * 512 + (ng * 64 + l) * 8];
#pragma unroll
            for (int mt = 0; mt < 2; mt++) {
                acc[mt][nt] = __builtin_amdgcn_mfma_f32_16x16x32_bf16(a_hi[mt], bh, acc[mt][nt], 0, 0, 0);
                acc[mt][nt] = __builtin_amdgcn_mfma_f32_16x16x32_bf16(a_hi[mt], bl, acc[mt][nt], 0, 0, 0);
                acc[mt][nt] = __builtin_amdgcn_mfma_f32_16x16x32_bf16(a_lo[mt], bh, acc[mt][nt], 0, 0, 0);
            }
        }
    }

    // epilogue: col = colofs + ng*16 + ln ; row = m0 + (mw*2+mt)*16 + q*4 + i
#pragma unroll
    for (int nt = 0; nt < NH; nt++) {
        int ng = nw * NH + nt;
        int col = colofs + ng * 16 + ln;
        float bv = bias[ng * 16 + ln];
#pragma unroll
        for (int mt = 0; mt < 2; mt++) {
            f32x4 v = acc[mt][nt];
#pragma unroll
            for (int i = 0; i < 4; i++) {
                int m = m0 + (mw * 2 + mt) * 16 + q * 4 + i;
                if (m < M) {
                    float xv = v[i] + bv;
                    if (ACT) xv = lrelu(xv);
                    C[(size_t)m * 128 + col] = xv;
                }
            }
        }
    }
}

// ---------------- small feature encoders (K=6, K=11) ----------------
__global__ __launch_bounds__(256) void encode_small(const float* __restrict__ num_prop,
                                                    const float* __restrict__ cat_prop,
                                                    const float* __restrict__ W_np,
                                                    const float* __restrict__ b_np,
                                                    const float* __restrict__ W_cp,
                                                    const float* __restrict__ b_cp,
                                                    float* __restrict__ x) {
    int t = blockIdx.x * 256 + threadIdx.x;
    int node = t >> 6;
    int jj = t & 63;
    if (node >= N_NODES) return;
    if (jj < 32) {
        float acc = b_np[jj];
        const float* row = num_prop + (size_t)node * 6;
#pragma unroll
        for (int k = 0; k < 6; k++) acc = fmaf(row[k], W_np[k * 32 + jj], acc);
        x[(size_t)node * 128 + 64 + jj] = lrelu(acc);
    } else {
        int j = jj - 32;
        float acc = b_cp[j];
        const float* row = cat_prop + (size_t)node * 11;
#pragma unroll
        for (int k = 0; k < 11; k++) acc = fmaf(row[k], W_cp[k * 32 + j], acc);
        x[(size_t)node * 128 + 96 + j] = lrelu(acc);
    }
}

// ---------------- final projection 128 -> 2 ----------------
__global__ __launch_bounds__(256) void out_proj(const float* __restrict__ X,
                                                const float* __restrict__ W,
                                                const float* __restrict__ b,
                                                float* __restrict__ out, int M) {
    int n = blockIdx.x * 256 + threadIdx.x;
    if (n >= M) return;
    float a0 = b[0], a1 = b[1];
    const float4* xr = (const float4*)(X + (size_t)n * 128);
#pragma unroll
    for (int k4 = 0; k4 < 32; k4++) {
        float4 v = xr[k4];
        a0 = fmaf(v.x, W[(k4 * 4 + 0) * 2 + 0], a0);
        a1 = fmaf(v.x, W[(k4 * 4 + 0) * 2 + 1], a1);
        a0 = fmaf(v.y, W[(k4 * 4 + 1) * 2 + 0], a0);
        a1 = fmaf(v.y, W[(k4 * 4 + 1) * 2 + 1], a1);
        a0 = fmaf(v.z, W[(k4 * 4 + 2) * 2 + 0], a0);
        a1 = fmaf(v.z, W[(k4 * 4 + 2) * 2 + 1], a1);
        a0 = fmaf(v.w, W[(k4 * 4 + 3) * 2 + 0], a0);
        a1 = fmaf(v.w, W[(k4 * 4 + 3) * 2 + 1], a1);
    }
    out[(size_t)n * 2 + 0] = a0;
    out[(size_t)n * 2 + 1] = a1;
}

static inline size_t align64(size_t x) { return (x + 63) & ~(size_t)63; }

extern "C" void kernel_launch(void* const* d_in, const int* in_sizes, int n_in,
                              void* d_out, int out_size, void* d_ws, size_t ws_size,
                              hipStream_t stream) {
    const float* des      = (const float*)d_in[0];
    const float* tweet    = (const float*)d_in[1];
    const float* num_prop = (const float*)d_in[2];
    const float* cat_prop = (const float*)d_in[3];
    const int*   edge_index = (const int*)d_in[4];
    const int*   edge_type  = (const int*)d_in[5];
    const float* W_des = (const float*)d_in[6];  const float* b_des = (const float*)d_in[7];
    const float* W_tw  = (const float*)d_in[8];  const float* b_tw  = (const float*)d_in[9];
    const float* W_np  = (const float*)d_in[10]; const float* b_np  = (const float*)d_in[11];
    const float* W_cp  = (const float*)d_in[12]; const float* b_cp  = (const float*)d_in[13];
    const float* W_in  = (const float*)d_in[14]; const float* b_in  = (const float*)d_in[15];
    const float* rel_w = (const float*)d_in[16]; const float* root_w = (const float*)d_in[17];
    const float* rgcn_b = (const float*)d_in[18];
    const float* W_o1  = (const float*)d_in[19]; const float* b_o1  = (const float*)d_in[20];
    const float* W_o2  = (const float*)d_in[21]; const float* b_o2  = (const float*)d_in[22];
    float* out = (float*)d_out;

    // workspace layout
    char* p = (char*)d_ws;
    float* agg = (float*)p;            p += (size_t)NSEG * 128 * 4;
    float* xA  = (float*)p;            p += (size_t)N_NODES * 128 * 4;
    float* xB  = (float*)p;            p += (size_t)N_NODES * 128 * 4;
    int* cnt       = (int*)p;          p += (size_t)NSEG * 4;
    int* rowptr    = (int*)p;          p += (size_t)(NSEG + 1) * 4;
    int* cursor    = (int*)p;          p += (size_t)NSEG * 4;
    int* srcSorted = (int*)p;          p += (size_t)N_EDGES * 4;
    int* blockSums = (int*)p;          p += (size_t)256 * 4;
    p = (char*)align64((size_t)p);
    // swizzled weights (shorts): chunk stride = 2*NTILES*512
    short* bz_dual = (short*)p;        p += (size_t)24 * 2 * 8 * 512 * 2;  // 20 (rel) + 4 (root)
    short* bz_in   = (short*)p;        p += (size_t)4 * 2 * 8 * 512 * 2;
    short* bz_o1   = (short*)p;        p += (size_t)4 * 2 * 8 * 512 * 2;
    short* bz_des  = (short*)p;        p += (size_t)24 * 2 * 2 * 512 * 2;
    short* bz_tw   = (short*)p;        p += (size_t)24 * 2 * 2 * 512 * 2;

    // 0. weight prep (swizzle to fragment order)
    build_bswz<<<(20 * 8 * 64 + 255) / 256, 256, 0, stream>>>(rel_w, 640, 128, 8, bz_dual);
    build_bswz<<<(4 * 8 * 64 + 255) / 256, 256, 0, stream>>>(root_w, 128, 128, 8,
                                                             bz_dual + (size_t)20 * 2 * 8 * 512);
    build_bswz<<<(4 * 8 * 64 + 255) / 256, 256, 0, stream>>>(W_in, 128, 128, 8, bz_in);
    build_bswz<<<(4 * 8 * 64 + 255) / 256, 256, 0, stream>>>(W_o1, 128, 128, 8, bz_o1);
    build_bswz<<<(24 * 2 * 64 + 255) / 256, 256, 0, stream>>>(W_des, 768, 32, 2, bz_des);
    build_bswz<<<(24 * 2 * 64 + 255) / 256, 256, 0, stream>>>(W_tw, 768, 32, 2, bz_tw);

    // 1. CSR build (layer-invariant)
    hipMemsetAsync(cnt, 0, (size_t)NSEG * sizeof(int), stream);
    hipMemsetAsync(cursor, 0, (size_t)NSEG * sizeof(int), stream);
    count_kernel<<<(N_EDGES + 255) / 256, 256, 0, stream>>>(edge_index, edge_type, cnt);
    scan1<<<SCAN_NB, SCAN_BS, 0, stream>>>(cnt, rowptr, blockSums);
    scan2<<<1, 256, 0, stream>>>(blockSums);
    scan3<<<SCAN_NB, SCAN_BS, 0, stream>>>(rowptr, blockSums);
    fill_kernel<<<(N_EDGES + 255) / 256, 256, 0, stream>>>(
        edge_index, edge_type, rowptr, cursor, srcSorted);

    // 2. encode
    encode_small<<<(N_NODES * 64 + 255) / 256, 256, 0, stream>>>(
        num_prop, cat_prop, W_np, b_np, W_cp, b_cp, xA);
    mfma_gemm<2, false, true><<<(N_NODES + 63) / 64, 256, 0, stream>>>(
        des, 768, nullptr, bz_des, b_des, xA, N_NODES, 0);
    mfma_gemm<2, false, true><<<(N_NODES + 63) / 64, 256, 0, stream>>>(
        tweet, 768, nullptr, bz_tw, b_tw, xA, N_NODES, 32);

    // 3. input linear
    mfma_gemm<8, false, true><<<(N_NODES + 63) / 64, 256, 0, stream>>>(
        xA, 128, nullptr, bz_in, b_in, xB, N_NODES, 0);

    // 4. RGCN x4
    float* cur = xB; float* nxt = xA;
    for (int l = 0; l < 4; l++) {
        agg_kernel<<<(NSEG * 32 + 255) / 256, 256, 0, stream>>>(cur, srcSorted, rowptr, agg);
        mfma_gemm<8, true, false><<<(N_NODES + 63) / 64, 256, 0, stream>>>(
            agg, 640, cur, bz_dual, rgcn_b, nxt, N_NODES, 0);
        float* tmp = cur; cur = nxt; nxt = tmp;
    }

    // 5. output head
    mfma_gemm<8, false, true><<<(N_NODES + 63) / 64, 256, 0, stream>>>(
        cur, 128, nullptr, bz_o1, b_o1, nxt, N_NODES, 0);
    out_proj<<<(N_NODES + 255) / 256, 256, 0, stream>>>(nxt, W_o2, b_o2, out, N_NODES);
}